// Round 4
// baseline (525.364 us; speedup 1.0000x reference)
//
#include <hip/hip_runtime.h>
#include <hip/hip_bf16.h>
#include <stdint.h>

// MoE: B=4,S=2048,D=1024,E=8,TOPK=2,I=938. Sparse top-2 routing + bf16 MFMA GEMMs.
// R4: gemm1 -> 128x128 dual (gate+up) accumulator tile; XCD-aware grid swizzle
//     on both GEMMs (blocks sharing an A-tile keep bid%8 constant and adjacent).

typedef __bf16 bf16_t;
typedef __bf16 bf16x8 __attribute__((ext_vector_type(8)));
typedef float  f32x4  __attribute__((ext_vector_type(4)));

#define TOKENS    8192
#define DMODEL    1024
#define NEXP      8
#define INTER     938
#define AP        1024     // padded inter dim (A cols / gemm2 K / Wd cols)
#define GUP       2048     // padded gate(1024)+up(1024) rows per expert
#define CAP_ROWS  17408    // 16384 + 8*128
#define MAX_TILES 136
#define SH_TILES  64       // 8192/128
#define TOT_TILES 200      // SH_TILES + MAX_TILES
#define BM        128
#define BK        64

#define PLAN_BLOCKS 16
#define TOK_PER_PLAN (TOKENS / PLAN_BLOCKS)

// ---- async global->LDS, 16B per lane; LDS dest = wave-uniform base + lane*16 ----
__device__ __forceinline__ void async16(const bf16_t* g, bf16_t* l) {
  __builtin_amdgcn_global_load_lds(
      (__attribute__((address_space(1))) void*)(g),
      (__attribute__((address_space(3))) void*)(l),
      16, 0, 0);
}

__device__ __forceinline__ unsigned short f2bu(float f) {
  bf16_t b = (bf16_t)f;
  unsigned short u;
  __builtin_memcpy(&u, &b, 2);
  return u;
}

// ---------------- weight re-layout converts ----------------
// gate_up [nExp,1876,1024] fp32 -> [nExp,2048,1024] bf16: rows 0..937 gate,
// 938..1023 zero, 1024..1961 up (src row r-86), 1962..2047 zero.
__global__ void conv_gu_pad(const float4* __restrict__ src, ushort4* __restrict__ dst) {
  int i = blockIdx.x * 256 + threadIdx.x;
  int e = i >> 19;            // GUP*256 = 2^19
  int rem = i & 524287;
  int r = rem >> 8;
  int c4 = rem & 255;
  const float4* s = src + (size_t)e * (1876 * 256);
  float4 v = {0.f, 0.f, 0.f, 0.f};
  if (r < INTER) v = s[r * 256 + c4];
  else if (r >= 1024 && r < 1024 + INTER) v = s[(r - 86) * 256 + c4];
  ushort4 o;
  o.x = f2bu(v.x); o.y = f2bu(v.y); o.z = f2bu(v.z); o.w = f2bu(v.w);
  dst[i] = o;
}

// down [nExp,1024,938] fp32 -> [nExp,1024,1024] bf16, cols >=938 zero
__global__ void conv_dn_pad(const float* __restrict__ src, bf16_t* __restrict__ dst) {
  int i = blockIdx.x * 256 + threadIdx.x;
  int e = i >> 20;
  int rem = i & 1048575;
  int n = rem >> 10;
  int c = rem & 1023;
  float v = (c < INTER) ? src[(size_t)e * (1024 * INTER) + n * INTER + c] : 0.f;
  dst[i] = (bf16_t)v;
}

// ---------------- routing ----------------
__global__ void init_kernel(int* __restrict__ row_token) {
  int i = blockIdx.x * 256 + threadIdx.x;
  if (i < CAP_ROWS) row_token[i] = -1;
}

// one wave per token: fp32 logits with full ILP, top-2, no atomics; emits Xb bf16.
__global__ __launch_bounds__(256) void router_kernel(
    const float4* __restrict__ X4, const float4* __restrict__ GW4,
    bf16_t* __restrict__ Xb, int* __restrict__ e01, float* __restrict__ w01) {
  int token = blockIdx.x * 4 + (threadIdx.x >> 6);
  int lane = threadIdx.x & 63;
  const float4* x4 = X4 + (size_t)token * 256;

  float4 xv[4];
#pragma unroll
  for (int j = 0; j < 4; j++) xv[j] = x4[lane + 64 * j];

  ushort4* xbrow = (ushort4*)(Xb + (size_t)token * DMODEL);
#pragma unroll
  for (int j = 0; j < 4; j++) {
    ushort4 r;
    r.x = f2bu(xv[j].x); r.y = f2bu(xv[j].y);
    r.z = f2bu(xv[j].z); r.w = f2bu(xv[j].w);
    xbrow[lane + 64 * j] = r;
  }

  float acc[NEXP];
#pragma unroll
  for (int e = 0; e < NEXP; e++) {
    float a = 0.f;
#pragma unroll
    for (int j = 0; j < 4; j++) {
      float4 g = GW4[e * 256 + lane + 64 * j];
      a += xv[j].x * g.x + xv[j].y * g.y + xv[j].z * g.z + xv[j].w * g.w;
    }
    acc[e] = a;
  }
#pragma unroll
  for (int off = 32; off > 0; off >>= 1)
#pragma unroll
    for (int e = 0; e < NEXP; e++) acc[e] += __shfl_down(acc[e], off, 64);

  if (lane == 0) {
    float mx = acc[0];
#pragma unroll
    for (int e = 1; e < NEXP; e++) mx = fmaxf(mx, acc[e]);
    float p[NEXP]; float s = 0.f;
#pragma unroll
    for (int e = 0; e < NEXP; e++) { p[e] = expf(acc[e] - mx); s += p[e]; }
    int i0 = 0;
#pragma unroll
    for (int e = 1; e < NEXP; e++) if (p[e] > p[i0]) i0 = e;
    int i1 = (i0 == 0) ? 1 : 0;
#pragma unroll
    for (int e = 0; e < NEXP; e++) if (e != i1 && e != i0 && p[e] > p[i1]) i1 = e;
    float p0 = p[i0] / s, p1 = p[i1] / s;
    float inv = 1.f / (p0 + p1 + 1e-8f);
    e01[token * 2 + 0] = i0; e01[token * 2 + 1] = i1;
    w01[token * 2 + 0] = p0 * inv; w01[token * 2 + 1] = p1 * inv;
  }
}

__global__ void hist_kernel(const int* __restrict__ e01, int* __restrict__ blockCounts) {
  __shared__ int h[NEXP];
  int t = threadIdx.x;
  if (t < NEXP) h[t] = 0;
  __syncthreads();
  int base = blockIdx.x * TOK_PER_PLAN * 2;
  for (int i = t; i < TOK_PER_PLAN * 2; i += 256) atomicAdd(&h[e01[base + i]], 1);
  __syncthreads();
  if (t < NEXP) blockCounts[blockIdx.x * NEXP + t] = h[t];
}

__global__ void offsets_kernel(const int* __restrict__ blockCounts, int* __restrict__ blockBase,
                               int* __restrict__ tileExpert, int* __restrict__ nTiles) {
  if (threadIdx.x != 0 || blockIdx.x != 0) return;
  int o = 0, t = 0;
  for (int e = 0; e < NEXP; e++) {
    int run = o, cnt = 0;
    for (int b = 0; b < PLAN_BLOCKS; b++) {
      blockBase[b * NEXP + e] = run;
      run += blockCounts[b * NEXP + e];
      cnt += blockCounts[b * NEXP + e];
    }
    int pad = (cnt + BM - 1) / BM * BM;
    for (int i = 0; i < pad / BM; i++) tileExpert[t++] = e;
    o += pad;
  }
  *nTiles = t;
}

// block-local ranks via LDS atomics; emits slotOf (token -> its 2 slot rows)
__global__ void scatter_kernel(const int* __restrict__ e01, const float* __restrict__ w01,
                               const int* __restrict__ blockBase,
                               int* __restrict__ row_token, float* __restrict__ row_weight,
                               int* __restrict__ slotOf) {
  __shared__ int cur[NEXP];
  __shared__ int base[NEXP];
  int t = threadIdx.x;
  if (t < NEXP) { cur[t] = 0; base[t] = blockBase[blockIdx.x * NEXP + t]; }
  __syncthreads();
  int tb = blockIdx.x * TOK_PER_PLAN;
  for (int i = t; i < TOK_PER_PLAN * 2; i += 256) {
    int e = e01[tb * 2 + i];
    int rank = atomicAdd(&cur[e], 1);
    int pos = base[e] + rank;
    row_token[pos] = tb + (i >> 1);
    row_weight[pos] = w01[tb * 2 + i];
    slotOf[tb * 2 + i] = pos;
  }
}

// XCD-aware decode: bid = s + 8*(f + 8*g); mtile = g*8+s keeps bid%8 fixed
// for all 8 f-blocks of one mtile -> same XCD L2, temporally adjacent.
__device__ __forceinline__ void decode_bid(int bid, int& mtile, int& f) {
  int s = bid & 7;
  f = (bid >> 3) & 7;
  mtile = (bid >> 6) * 8 + s;
}

// ---------------- GEMM1 (fused shared+routed): A[M,1024] = swiglu(X @ Wgu^T) ----------------
// tile: 128 rows x 128 inter-cols, dual accumulators (gate+up). 4 waves 2x2.
__global__ __launch_bounds__(256) void gemm1_fused(
    const bf16_t* __restrict__ Xb, const bf16_t* __restrict__ WS,
    const bf16_t* __restrict__ WE, bf16_t* __restrict__ As, bf16_t* __restrict__ Ar,
    const int* __restrict__ row_token, const int* __restrict__ tileExpert,
    const int* __restrict__ nTilesPtr) {
  int mt, fb;
  decode_bid(blockIdx.x, mt, fb);
  const bf16_t* W; bf16_t* Aout; int m0; const int* rtok = nullptr;
  if (mt < SH_TILES) {
    m0 = mt * BM; W = WS; Aout = As;
  } else {
    int rt = mt - SH_TILES;
    if (rt >= *nTilesPtr) return;
    m0 = rt * BM; W = WE + (size_t)tileExpert[rt] * (GUP * DMODEL);
    Aout = Ar; rtok = row_token;
  }
  const int f0 = fb * 128;

  __shared__ bf16_t sA[128 * BK];    // 16KB
  __shared__ bf16_t sBg[128 * BK];   // 16KB
  __shared__ bf16_t sBu[128 * BK];   // 16KB

  const int tid = threadIdx.x;
  const int w = tid >> 6, lane = tid & 63;

  const bf16_t* aptr[4];
#pragma unroll
  for (int i = 0; i < 4; i++) {
    int q = (i * 4 + w) * 64 + lane;
    int row = q >> 3, cc = ((q & 7) ^ (row & 7)) * 8;   // XOR swizzle
    int tok = m0 + row;
    if (rtok) { int t = rtok[tok]; tok = (t < 0) ? 0 : t; }
    aptr[i] = Xb + (size_t)tok * DMODEL + cc;
  }
  const bf16_t* bgp[4]; const bf16_t* bup[4];
#pragma unroll
  for (int i = 0; i < 4; i++) {
    int q = (i * 4 + w) * 64 + lane;
    int r = q >> 3, cc = ((q & 7) ^ (r & 7)) * 8;
    bgp[i] = W + (size_t)(f0 + r) * DMODEL + cc;
    bup[i] = W + (size_t)(1024 + f0 + r) * DMODEL + cc;
  }

  f32x4 accG[4][4], accU[4][4];
#pragma unroll
  for (int mi = 0; mi < 4; mi++)
#pragma unroll
    for (int ni = 0; ni < 4; ni++) {
      accG[mi][ni] = (f32x4){0.f, 0.f, 0.f, 0.f};
      accU[mi][ni] = (f32x4){0.f, 0.f, 0.f, 0.f};
    }

  const int wm = w >> 1, wn = w & 1;
  const int lr = lane & 15, quad = lane >> 4;

  for (int k0 = 0; k0 < DMODEL; k0 += BK) {
#pragma unroll
    for (int i = 0; i < 4; i++) async16(aptr[i] + k0, &sA[(i * 4 + w) * 512]);
#pragma unroll
    for (int i = 0; i < 4; i++) {
      async16(bgp[i] + k0, &sBg[(i * 4 + w) * 512]);
      async16(bup[i] + k0, &sBu[(i * 4 + w) * 512]);
    }
    __syncthreads();
#pragma unroll
    for (int kk = 0; kk < BK; kk += 32) {
      const int colsw = (((kk >> 3) + quad) ^ (lr & 7)) * 8;
      bf16x8 av[4], bg[4], bu[4];
#pragma unroll
      for (int mi = 0; mi < 4; mi++)
        av[mi] = *(const bf16x8*)&sA[(wm * 64 + mi * 16 + lr) * BK + colsw];
#pragma unroll
      for (int ni = 0; ni < 4; ni++) {
        bg[ni] = *(const bf16x8*)&sBg[(wn * 64 + ni * 16 + lr) * BK + colsw];
        bu[ni] = *(const bf16x8*)&sBu[(wn * 64 + ni * 16 + lr) * BK + colsw];
      }
#pragma unroll
      for (int mi = 0; mi < 4; mi++)
#pragma unroll
        for (int ni = 0; ni < 4; ni++) {
          accG[mi][ni] = __builtin_amdgcn_mfma_f32_16x16x32_bf16(av[mi], bg[ni], accG[mi][ni], 0, 0, 0);
          accU[mi][ni] = __builtin_amdgcn_mfma_f32_16x16x32_bf16(av[mi], bu[ni], accU[mi][ni], 0, 0, 0);
        }
    }
    __syncthreads();
  }

  // C/D layout: col=lane&15, row=quad*4+reg
#pragma unroll
  for (int mi = 0; mi < 4; mi++)
#pragma unroll
    for (int ni = 0; ni < 4; ni++)
#pragma unroll
      for (int r = 0; r < 4; r++) {
        int row = m0 + wm * 64 + mi * 16 + quad * 4 + r;
        int col = f0 + wn * 64 + ni * 16 + lr;
        float g = accG[mi][ni][r], u = accU[mi][ni][r];
        float v = (col < INTER) ? (g / (1.f + __expf(-g))) * u : 0.f;
        Aout[(size_t)row * AP + col] = (bf16_t)v;
      }
}

// ---------------- GEMM2 (fused shared+routed): 128x128 tile ----------------
__global__ __launch_bounds__(256) void gemm2_fused(
    const bf16_t* __restrict__ As, const bf16_t* __restrict__ Ar,
    const bf16_t* __restrict__ WS, const bf16_t* __restrict__ WE,
    float* __restrict__ Out, bf16_t* __restrict__ Yr,
    const float* __restrict__ row_weight, const int* __restrict__ tileExpert,
    const int* __restrict__ nTilesPtr) {
  int mt, fb;
  decode_bid(blockIdx.x, mt, fb);
  const bf16_t* A; const bf16_t* W; int m0; bool routed;
  if (mt < SH_TILES) {
    routed = false; m0 = mt * BM; A = As; W = WS;
  } else {
    int rt = mt - SH_TILES;
    if (rt >= *nTilesPtr) return;
    routed = true; m0 = rt * BM; A = Ar;
    W = WE + (size_t)tileExpert[rt] * (DMODEL * AP);
  }
  const int n0 = fb * 128;

  __shared__ bf16_t sA[128 * BK];   // 16KB
  __shared__ bf16_t sB[128 * BK];   // 16KB

  const int tid = threadIdx.x;
  const int w = tid >> 6, lane = tid & 63;

  const bf16_t* aptr[4];
#pragma unroll
  for (int i = 0; i < 4; i++) {
    int q = (i * 4 + w) * 64 + lane;
    int row = q >> 3, cc = ((q & 7) ^ (row & 7)) * 8;
    aptr[i] = A + (size_t)(m0 + row) * AP + cc;
  }
  const bf16_t* bp[4];
#pragma unroll
  for (int i = 0; i < 4; i++) {
    int q = (i * 4 + w) * 64 + lane;
    int r = q >> 3, cc = ((q & 7) ^ (r & 7)) * 8;
    bp[i] = W + (size_t)(n0 + r) * AP + cc;
  }

  f32x4 acc[4][4];
#pragma unroll
  for (int mi = 0; mi < 4; mi++)
#pragma unroll
    for (int ni = 0; ni < 4; ni++) acc[mi][ni] = (f32x4){0.f, 0.f, 0.f, 0.f};

  const int wm = w >> 1, wn = w & 1;
  const int lr = lane & 15, quad = lane >> 4;

  for (int k0 = 0; k0 < AP; k0 += BK) {
#pragma unroll
    for (int i = 0; i < 4; i++) async16(aptr[i] + k0, &sA[(i * 4 + w) * 512]);
#pragma unroll
    for (int i = 0; i < 4; i++) async16(bp[i] + k0, &sB[(i * 4 + w) * 512]);
    __syncthreads();
#pragma unroll
    for (int kk = 0; kk < BK; kk += 32) {
      const int colsw = (((kk >> 3) + quad) ^ (lr & 7)) * 8;
      bf16x8 av[4], bv[4];
#pragma unroll
      for (int mi = 0; mi < 4; mi++)
        av[mi] = *(const bf16x8*)&sA[(wm * 64 + mi * 16 + lr) * BK + colsw];
#pragma unroll
      for (int ni = 0; ni < 4; ni++)
        bv[ni] = *(const bf16x8*)&sB[(wn * 64 + ni * 16 + lr) * BK + colsw];
#pragma unroll
      for (int mi = 0; mi < 4; mi++)
#pragma unroll
        for (int ni = 0; ni < 4; ni++)
          acc[mi][ni] = __builtin_amdgcn_mfma_f32_16x16x32_bf16(av[mi], bv[ni], acc[mi][ni], 0, 0, 0);
    }
    __syncthreads();
  }

#pragma unroll
  for (int mi = 0; mi < 4; mi++) {
#pragma unroll
    for (int r = 0; r < 4; r++) {
      int row = m0 + wm * 64 + mi * 16 + quad * 4 + r;
      float rw = routed ? row_weight[row] : 0.f;
#pragma unroll
      for (int ni = 0; ni < 4; ni++) {
        int col = n0 + wn * 64 + ni * 16 + lr;
        float v = acc[mi][ni][r];
        if (!routed) Out[(size_t)row * DMODEL + col] = v;
        else         Yr[(size_t)row * DMODEL + col] = (bf16_t)(rw * v);
      }
    }
  }
}

// ---------------- combine: Out[t] += Yr[slot0(t)] + Yr[slot1(t)] ----------------
__global__ __launch_bounds__(256) void combine_kernel(
    float4* __restrict__ Out4, const ushort4* __restrict__ Yr4,
    const int* __restrict__ slotOf) {
  int t = blockIdx.x;
  int c = threadIdx.x;
  int s0 = slotOf[t * 2 + 0];
  int s1 = slotOf[t * 2 + 1];
  float4 o = Out4[t * 256 + c];
  ushort4 a = Yr4[(size_t)s0 * 256 + c];
  ushort4 b = Yr4[(size_t)s1 * 256 + c];
  union { unsigned int u; float f; } cv;
  auto b2f = [&](unsigned short x) { cv.u = ((unsigned int)x) << 16; return cv.f; };
  o.x += b2f(a.x) + b2f(b.x);
  o.y += b2f(a.y) + b2f(b.y);
  o.z += b2f(a.z) + b2f(b.z);
  o.w += b2f(a.w) + b2f(b.w);
  Out4[t * 256 + c] = o;
}

// ---------------- launch ----------------
extern "C" void kernel_launch(void* const* d_in, const int* in_sizes, int n_in,
                              void* d_out, int out_size, void* d_ws, size_t ws_size,
                              hipStream_t stream) {
  const float* X   = (const float*)d_in[0];
  const float* GW  = (const float*)d_in[1];
  const float* SGU = (const float*)d_in[2];
  const float* SD  = (const float*)d_in[3];
  const float* EGU = (const float*)d_in[4];
  const float* ED  = (const float*)d_in[5];
  float* Out = (float*)d_out;

  char* ws = (char*)d_ws;
  size_t o = 0;
  auto alloc = [&](size_t b) -> char* {
    char* p = ws + o;
    o = (o + b + 255) & ~(size_t)255;
    return p;
  };
  bf16_t* Xb    = (bf16_t*)alloc((size_t)TOKENS * DMODEL * 2);          // 16.8 MB
  bf16_t* WguSP = (bf16_t*)alloc((size_t)GUP * DMODEL * 2);             // 4.2 MB
  bf16_t* WdSP  = (bf16_t*)alloc((size_t)DMODEL * AP * 2);              // 2.1 MB
  bf16_t* WguEP = (bf16_t*)alloc((size_t)NEXP * GUP * DMODEL * 2);      // 33.6 MB
  bf16_t* WdEP  = (bf16_t*)alloc((size_t)NEXP * DMODEL * AP * 2);       // 16.8 MB
  bf16_t* As    = (bf16_t*)alloc((size_t)TOKENS * AP * 2);              // 16.8 MB
  bf16_t* Ar    = (bf16_t*)alloc((size_t)CAP_ROWS * AP * 2);            // 35.7 MB
  bf16_t* Yr    = (bf16_t*)alloc((size_t)CAP_ROWS * DMODEL * 2);        // 35.7 MB
  int*    e01    = (int*)alloc(TOKENS * 2 * 4);
  float*  w01    = (float*)alloc(TOKENS * 2 * 4);
  int*    slotOf = (int*)alloc(TOKENS * 2 * 4);
  int*    blkCnt = (int*)alloc(PLAN_BLOCKS * NEXP * 4);
  int*    blkBas = (int*)alloc(PLAN_BLOCKS * NEXP * 4);
  int*    nTiles = (int*)alloc(64);
  int*    tileEx = (int*)alloc(MAX_TILES * 4);
  int*    rowTok = (int*)alloc(CAP_ROWS * 4);
  float*  rowW   = (float*)alloc(CAP_ROWS * 4);
  (void)ws_size; (void)in_sizes; (void)n_in; (void)out_size;

  // weight re-layout (padded)
  conv_gu_pad<<<2048, 256, 0, stream>>>((const float4*)SGU, (ushort4*)WguSP);
  conv_gu_pad<<<NEXP * 2048, 256, 0, stream>>>((const float4*)EGU, (ushort4*)WguEP);
  conv_dn_pad<<<4096, 256, 0, stream>>>(SD, WdSP);
  conv_dn_pad<<<NEXP * 4096, 256, 0, stream>>>(ED, WdEP);

  // routing
  init_kernel<<<(CAP_ROWS + 255) / 256, 256, 0, stream>>>(rowTok);
  router_kernel<<<TOKENS / 4, 256, 0, stream>>>(
      (const float4*)X, (const float4*)GW, Xb, e01, w01);
  hist_kernel<<<PLAN_BLOCKS, 256, 0, stream>>>(e01, blkCnt);
  offsets_kernel<<<1, 64, 0, stream>>>(blkCnt, blkBas, tileEx, nTiles);
  scatter_kernel<<<PLAN_BLOCKS, 256, 0, stream>>>(e01, w01, blkBas, rowTok, rowW, slotOf);

  // GEMMs: 1D grids, XCD-swizzled (TOT_TILES=200 mtiles x 8 f-blocks = 1600)
  gemm1_fused<<<TOT_TILES * 8, 256, 0, stream>>>(
      Xb, WguSP, WguEP, As, Ar, rowTok, tileEx, nTiles);
  gemm2_fused<<<TOT_TILES * 8, 256, 0, stream>>>(
      As, Ar, WdSP, WdEP, Out, Yr, rowW, tileEx, nTiles);
  combine_kernel<<<TOKENS, 256, 0, stream>>>((float4*)Out, (const ushort4*)Yr, slotOf);
}

// Round 5
// 462.832 us; speedup vs baseline: 1.1351x; 1.1351x over previous
//
#include <hip/hip_runtime.h>
#include <hip/hip_bf16.h>
#include <stdint.h>

// MoE: B=4,S=2048,D=1024,E=8,TOPK=2,I=938. Sparse top-2 routing + bf16 MFMA GEMMs.
// R5: revert gemm1 to 128x64 dual-acc tile (R3; 32KB LDS, occupancy ~5 blk/CU);
//     f-fastest grid ordering (A-tile L2 locality); skip pure-pad f-block in
//     gemm1 and pad K-steps in gemm2 (Wd pad cols are zero).

typedef __bf16 bf16_t;
typedef __bf16 bf16x8 __attribute__((ext_vector_type(8)));
typedef float  f32x4  __attribute__((ext_vector_type(4)));

#define TOKENS    8192
#define DMODEL    1024
#define NEXP      8
#define INTER     938
#define AP        1024     // padded inter dim (A cols / gemm2 K / Wd cols)
#define KP2       960      // gemm2 effective K (A cols >=960 never written)
#define GUP       2048     // padded gate(1024)+up(1024) rows per expert
#define CAP_ROWS  17408    // 16384 + 8*128
#define MAX_TILES 136
#define SH_TILES  64       // 8192/128
#define TOT_TILES 200      // SH_TILES + MAX_TILES
#define BM        128
#define BK        64

#define PLAN_BLOCKS 16
#define TOK_PER_PLAN (TOKENS / PLAN_BLOCKS)

// ---- async global->LDS, 16B per lane; LDS dest = wave-uniform base + lane*16 ----
__device__ __forceinline__ void async16(const bf16_t* g, bf16_t* l) {
  __builtin_amdgcn_global_load_lds(
      (__attribute__((address_space(1))) void*)(g),
      (__attribute__((address_space(3))) void*)(l),
      16, 0, 0);
}

__device__ __forceinline__ unsigned short f2bu(float f) {
  bf16_t b = (bf16_t)f;
  unsigned short u;
  __builtin_memcpy(&u, &b, 2);
  return u;
}

// ---------------- weight re-layout converts ----------------
// gate_up [nExp,1876,1024] fp32 -> [nExp,2048,1024] bf16: rows 0..937 gate,
// 938..1023 zero, 1024..1961 up (src row r-86), 1962..2047 zero.
__global__ void conv_gu_pad(const float4* __restrict__ src, ushort4* __restrict__ dst) {
  int i = blockIdx.x * 256 + threadIdx.x;
  int e = i >> 19;            // GUP*256 = 2^19
  int rem = i & 524287;
  int r = rem >> 8;
  int c4 = rem & 255;
  const float4* s = src + (size_t)e * (1876 * 256);
  float4 v = {0.f, 0.f, 0.f, 0.f};
  if (r < INTER) v = s[r * 256 + c4];
  else if (r >= 1024 && r < 1024 + INTER) v = s[(r - 86) * 256 + c4];
  ushort4 o;
  o.x = f2bu(v.x); o.y = f2bu(v.y); o.z = f2bu(v.z); o.w = f2bu(v.w);
  dst[i] = o;
}

// down [nExp,1024,938] fp32 -> [nExp,1024,1024] bf16, cols >=938 zero
__global__ void conv_dn_pad(const float* __restrict__ src, bf16_t* __restrict__ dst) {
  int i = blockIdx.x * 256 + threadIdx.x;
  int e = i >> 20;
  int rem = i & 1048575;
  int n = rem >> 10;
  int c = rem & 1023;
  float v = (c < INTER) ? src[(size_t)e * (1024 * INTER) + n * INTER + c] : 0.f;
  dst[i] = (bf16_t)v;
}

// ---------------- routing ----------------
__global__ void init_kernel(int* __restrict__ row_token) {
  int i = blockIdx.x * 256 + threadIdx.x;
  if (i < CAP_ROWS) row_token[i] = -1;
}

// one wave per token: fp32 logits with full ILP, top-2, no atomics; emits Xb bf16.
__global__ __launch_bounds__(256) void router_kernel(
    const float4* __restrict__ X4, const float4* __restrict__ GW4,
    bf16_t* __restrict__ Xb, int* __restrict__ e01, float* __restrict__ w01) {
  int token = blockIdx.x * 4 + (threadIdx.x >> 6);
  int lane = threadIdx.x & 63;
  const float4* x4 = X4 + (size_t)token * 256;

  float4 xv[4];
#pragma unroll
  for (int j = 0; j < 4; j++) xv[j] = x4[lane + 64 * j];

  ushort4* xbrow = (ushort4*)(Xb + (size_t)token * DMODEL);
#pragma unroll
  for (int j = 0; j < 4; j++) {
    ushort4 r;
    r.x = f2bu(xv[j].x); r.y = f2bu(xv[j].y);
    r.z = f2bu(xv[j].z); r.w = f2bu(xv[j].w);
    xbrow[lane + 64 * j] = r;
  }

  float acc[NEXP];
#pragma unroll
  for (int e = 0; e < NEXP; e++) {
    float a = 0.f;
#pragma unroll
    for (int j = 0; j < 4; j++) {
      float4 g = GW4[e * 256 + lane + 64 * j];
      a += xv[j].x * g.x + xv[j].y * g.y + xv[j].z * g.z + xv[j].w * g.w;
    }
    acc[e] = a;
  }
#pragma unroll
  for (int off = 32; off > 0; off >>= 1)
#pragma unroll
    for (int e = 0; e < NEXP; e++) acc[e] += __shfl_down(acc[e], off, 64);

  if (lane == 0) {
    float mx = acc[0];
#pragma unroll
    for (int e = 1; e < NEXP; e++) mx = fmaxf(mx, acc[e]);
    float p[NEXP]; float s = 0.f;
#pragma unroll
    for (int e = 0; e < NEXP; e++) { p[e] = expf(acc[e] - mx); s += p[e]; }
    int i0 = 0;
#pragma unroll
    for (int e = 1; e < NEXP; e++) if (p[e] > p[i0]) i0 = e;
    int i1 = (i0 == 0) ? 1 : 0;
#pragma unroll
    for (int e = 0; e < NEXP; e++) if (e != i1 && e != i0 && p[e] > p[i1]) i1 = e;
    float p0 = p[i0] / s, p1 = p[i1] / s;
    float inv = 1.f / (p0 + p1 + 1e-8f);
    e01[token * 2 + 0] = i0; e01[token * 2 + 1] = i1;
    w01[token * 2 + 0] = p0 * inv; w01[token * 2 + 1] = p1 * inv;
  }
}

__global__ void hist_kernel(const int* __restrict__ e01, int* __restrict__ blockCounts) {
  __shared__ int h[NEXP];
  int t = threadIdx.x;
  if (t < NEXP) h[t] = 0;
  __syncthreads();
  int base = blockIdx.x * TOK_PER_PLAN * 2;
  for (int i = t; i < TOK_PER_PLAN * 2; i += 256) atomicAdd(&h[e01[base + i]], 1);
  __syncthreads();
  if (t < NEXP) blockCounts[blockIdx.x * NEXP + t] = h[t];
}

__global__ void offsets_kernel(const int* __restrict__ blockCounts, int* __restrict__ blockBase,
                               int* __restrict__ tileExpert, int* __restrict__ nTiles) {
  if (threadIdx.x != 0 || blockIdx.x != 0) return;
  int o = 0, t = 0;
  for (int e = 0; e < NEXP; e++) {
    int run = o, cnt = 0;
    for (int b = 0; b < PLAN_BLOCKS; b++) {
      blockBase[b * NEXP + e] = run;
      run += blockCounts[b * NEXP + e];
      cnt += blockCounts[b * NEXP + e];
    }
    int pad = (cnt + BM - 1) / BM * BM;
    for (int i = 0; i < pad / BM; i++) tileExpert[t++] = e;
    o += pad;
  }
  *nTiles = t;
}

// block-local ranks via LDS atomics; emits slotOf (token -> its 2 slot rows)
__global__ void scatter_kernel(const int* __restrict__ e01, const float* __restrict__ w01,
                               const int* __restrict__ blockBase,
                               int* __restrict__ row_token, float* __restrict__ row_weight,
                               int* __restrict__ slotOf) {
  __shared__ int cur[NEXP];
  __shared__ int base[NEXP];
  int t = threadIdx.x;
  if (t < NEXP) { cur[t] = 0; base[t] = blockBase[blockIdx.x * NEXP + t]; }
  __syncthreads();
  int tb = blockIdx.x * TOK_PER_PLAN;
  for (int i = t; i < TOK_PER_PLAN * 2; i += 256) {
    int e = e01[tb * 2 + i];
    int rank = atomicAdd(&cur[e], 1);
    int pos = base[e] + rank;
    row_token[pos] = tb + (i >> 1);
    row_weight[pos] = w01[tb * 2 + i];
    slotOf[tb * 2 + i] = pos;
  }
}

// ---------------- GEMM1 (fused shared+routed): A[M,960] = swiglu(X @ Wgu^T) ----------------
// tile 128 x (64 gate + 64 up), BK=64; 4 waves 2x2; XOR-swizzled LDS.
// grid: (15, nMtiles) -- f fastest for A-tile L2 locality; f=15 (pure pad) skipped.
__global__ __launch_bounds__(256) void gemm1_fused(
    const bf16_t* __restrict__ Xb, const bf16_t* __restrict__ WS,
    const bf16_t* __restrict__ WE, bf16_t* __restrict__ As, bf16_t* __restrict__ Ar,
    const int* __restrict__ row_token, const int* __restrict__ tileExpert,
    const int* __restrict__ nTilesPtr) {
  const int mt = blockIdx.y;
  const bf16_t* W; bf16_t* Aout; int m0; const int* rtok = nullptr;
  if (mt < SH_TILES) {
    m0 = mt * BM; W = WS; Aout = As;
  } else {
    int rt = mt - SH_TILES;
    if (rt >= *nTilesPtr) return;
    m0 = rt * BM; W = WE + (size_t)tileExpert[rt] * (GUP * DMODEL);
    Aout = Ar; rtok = row_token;
  }
  const int f0 = blockIdx.x * 64;

  __shared__ bf16_t sA[BM * BK];    // 16KB
  __shared__ bf16_t sBg[64 * BK];   // 8KB
  __shared__ bf16_t sBu[64 * BK];   // 8KB

  const int tid = threadIdx.x;
  const int w = tid >> 6, lane = tid & 63;

  const bf16_t* aptr[4];
#pragma unroll
  for (int i = 0; i < 4; i++) {
    int q = (i * 4 + w) * 64 + lane;
    int row = q >> 3, cc = ((q & 7) ^ (row & 7)) * 8;   // XOR swizzle
    int tok = m0 + row;
    if (rtok) { int t = rtok[tok]; tok = (t < 0) ? 0 : t; }
    aptr[i] = Xb + (size_t)tok * DMODEL + cc;
  }
  const bf16_t* bgp[2]; const bf16_t* bup[2];
#pragma unroll
  for (int i = 0; i < 2; i++) {
    int q = (i * 4 + w) * 64 + lane;
    int r = q >> 3, cc = ((q & 7) ^ (r & 7)) * 8;
    bgp[i] = W + (size_t)(f0 + r) * DMODEL + cc;
    bup[i] = W + (size_t)(1024 + f0 + r) * DMODEL + cc;
  }

  f32x4 accG[4][2], accU[4][2];
#pragma unroll
  for (int mi = 0; mi < 4; mi++)
#pragma unroll
    for (int ni = 0; ni < 2; ni++) {
      accG[mi][ni] = (f32x4){0.f, 0.f, 0.f, 0.f};
      accU[mi][ni] = (f32x4){0.f, 0.f, 0.f, 0.f};
    }

  const int wm = w >> 1, wn = w & 1;
  const int lr = lane & 15, quad = lane >> 4;

  for (int k0 = 0; k0 < DMODEL; k0 += BK) {
#pragma unroll
    for (int i = 0; i < 4; i++) async16(aptr[i] + k0, &sA[(i * 4 + w) * 512]);
#pragma unroll
    for (int i = 0; i < 2; i++) {
      async16(bgp[i] + k0, &sBg[(i * 4 + w) * 512]);
      async16(bup[i] + k0, &sBu[(i * 4 + w) * 512]);
    }
    __syncthreads();
#pragma unroll
    for (int kk = 0; kk < BK; kk += 32) {
      const int colsw = (((kk >> 3) + quad) ^ (lr & 7)) * 8;
      bf16x8 av[4], bg[2], bu[2];
#pragma unroll
      for (int mi = 0; mi < 4; mi++)
        av[mi] = *(const bf16x8*)&sA[(wm * 64 + mi * 16 + lr) * BK + colsw];
#pragma unroll
      for (int ni = 0; ni < 2; ni++) {
        bg[ni] = *(const bf16x8*)&sBg[(wn * 32 + ni * 16 + lr) * BK + colsw];
        bu[ni] = *(const bf16x8*)&sBu[(wn * 32 + ni * 16 + lr) * BK + colsw];
      }
#pragma unroll
      for (int mi = 0; mi < 4; mi++)
#pragma unroll
        for (int ni = 0; ni < 2; ni++) {
          accG[mi][ni] = __builtin_amdgcn_mfma_f32_16x16x32_bf16(av[mi], bg[ni], accG[mi][ni], 0, 0, 0);
          accU[mi][ni] = __builtin_amdgcn_mfma_f32_16x16x32_bf16(av[mi], bu[ni], accU[mi][ni], 0, 0, 0);
        }
    }
    __syncthreads();
  }

  // C/D layout: col=lane&15, row=quad*4+reg
#pragma unroll
  for (int mi = 0; mi < 4; mi++)
#pragma unroll
    for (int ni = 0; ni < 2; ni++)
#pragma unroll
      for (int r = 0; r < 4; r++) {
        int row = m0 + wm * 64 + mi * 16 + quad * 4 + r;
        int col = f0 + wn * 32 + ni * 16 + lr;
        float g = accG[mi][ni][r], u = accU[mi][ni][r];
        float v = (col < INTER) ? (g / (1.f + __expf(-g))) * u : 0.f;
        Aout[(size_t)row * AP + col] = (bf16_t)v;
      }
}

// ---------------- GEMM2 (fused shared+routed): 128x128 tile, K=960 ----------------
// grid: (8, nMtiles) -- f fastest.
__global__ __launch_bounds__(256) void gemm2_fused(
    const bf16_t* __restrict__ As, const bf16_t* __restrict__ Ar,
    const bf16_t* __restrict__ WS, const bf16_t* __restrict__ WE,
    float* __restrict__ Out, bf16_t* __restrict__ Yr,
    const float* __restrict__ row_weight, const int* __restrict__ tileExpert,
    const int* __restrict__ nTilesPtr) {
  const int mt = blockIdx.y;
  const bf16_t* A; const bf16_t* W; int m0; bool routed;
  if (mt < SH_TILES) {
    routed = false; m0 = mt * BM; A = As; W = WS;
  } else {
    int rt = mt - SH_TILES;
    if (rt >= *nTilesPtr) return;
    routed = true; m0 = rt * BM; A = Ar;
    W = WE + (size_t)tileExpert[rt] * (DMODEL * AP);
  }
  const int n0 = blockIdx.x * 128;

  __shared__ bf16_t sA[128 * BK];   // 16KB
  __shared__ bf16_t sB[128 * BK];   // 16KB

  const int tid = threadIdx.x;
  const int w = tid >> 6, lane = tid & 63;

  const bf16_t* aptr[4];
#pragma unroll
  for (int i = 0; i < 4; i++) {
    int q = (i * 4 + w) * 64 + lane;
    int row = q >> 3, cc = ((q & 7) ^ (row & 7)) * 8;
    aptr[i] = A + (size_t)(m0 + row) * AP + cc;
  }
  const bf16_t* bp[4];
#pragma unroll
  for (int i = 0; i < 4; i++) {
    int q = (i * 4 + w) * 64 + lane;
    int r = q >> 3, cc = ((q & 7) ^ (r & 7)) * 8;
    bp[i] = W + (size_t)(n0 + r) * AP + cc;
  }

  f32x4 acc[4][4];
#pragma unroll
  for (int mi = 0; mi < 4; mi++)
#pragma unroll
    for (int ni = 0; ni < 4; ni++) acc[mi][ni] = (f32x4){0.f, 0.f, 0.f, 0.f};

  const int wm = w >> 1, wn = w & 1;
  const int lr = lane & 15, quad = lane >> 4;

  for (int k0 = 0; k0 < KP2; k0 += BK) {
#pragma unroll
    for (int i = 0; i < 4; i++) async16(aptr[i] + k0, &sA[(i * 4 + w) * 512]);
#pragma unroll
    for (int i = 0; i < 4; i++) async16(bp[i] + k0, &sB[(i * 4 + w) * 512]);
    __syncthreads();
#pragma unroll
    for (int kk = 0; kk < BK; kk += 32) {
      const int colsw = (((kk >> 3) + quad) ^ (lr & 7)) * 8;
      bf16x8 av[4], bv[4];
#pragma unroll
      for (int mi = 0; mi < 4; mi++)
        av[mi] = *(const bf16x8*)&sA[(wm * 64 + mi * 16 + lr) * BK + colsw];
#pragma unroll
      for (int ni = 0; ni < 4; ni++)
        bv[ni] = *(const bf16x8*)&sB[(wn * 64 + ni * 16 + lr) * BK + colsw];
#pragma unroll
      for (int mi = 0; mi < 4; mi++)
#pragma unroll
        for (int ni = 0; ni < 4; ni++)
          acc[mi][ni] = __builtin_amdgcn_mfma_f32_16x16x32_bf16(av[mi], bv[ni], acc[mi][ni], 0, 0, 0);
    }
    __syncthreads();
  }

#pragma unroll
  for (int mi = 0; mi < 4; mi++) {
#pragma unroll
    for (int r = 0; r < 4; r++) {
      int row = m0 + wm * 64 + mi * 16 + quad * 4 + r;
      float rw = routed ? row_weight[row] : 0.f;
#pragma unroll
      for (int ni = 0; ni < 4; ni++) {
        int col = n0 + wn * 64 + ni * 16 + lr;
        float v = acc[mi][ni][r];
        if (!routed) Out[(size_t)row * DMODEL + col] = v;
        else         Yr[(size_t)row * DMODEL + col] = (bf16_t)(rw * v);
      }
    }
  }
}

// ---------------- combine: Out[t] += Yr[slot0(t)] + Yr[slot1(t)] ----------------
__global__ __launch_bounds__(256) void combine_kernel(
    float4* __restrict__ Out4, const ushort4* __restrict__ Yr4,
    const int* __restrict__ slotOf) {
  int t = blockIdx.x;
  int c = threadIdx.x;
  int s0 = slotOf[t * 2 + 0];
  int s1 = slotOf[t * 2 + 1];
  float4 o = Out4[t * 256 + c];
  ushort4 a = Yr4[(size_t)s0 * 256 + c];
  ushort4 b = Yr4[(size_t)s1 * 256 + c];
  union { unsigned int u; float f; } cv;
  auto b2f = [&](unsigned short x) { cv.u = ((unsigned int)x) << 16; return cv.f; };
  o.x += b2f(a.x) + b2f(b.x);
  o.y += b2f(a.y) + b2f(b.y);
  o.z += b2f(a.z) + b2f(b.z);
  o.w += b2f(a.w) + b2f(b.w);
  Out4[t * 256 + c] = o;
}

// ---------------- launch ----------------
extern "C" void kernel_launch(void* const* d_in, const int* in_sizes, int n_in,
                              void* d_out, int out_size, void* d_ws, size_t ws_size,
                              hipStream_t stream) {
  const float* X   = (const float*)d_in[0];
  const float* GW  = (const float*)d_in[1];
  const float* SGU = (const float*)d_in[2];
  const float* SD  = (const float*)d_in[3];
  const float* EGU = (const float*)d_in[4];
  const float* ED  = (const float*)d_in[5];
  float* Out = (float*)d_out;

  char* ws = (char*)d_ws;
  size_t o = 0;
  auto alloc = [&](size_t b) -> char* {
    char* p = ws + o;
    o = (o + b + 255) & ~(size_t)255;
    return p;
  };
  bf16_t* Xb    = (bf16_t*)alloc((size_t)TOKENS * DMODEL * 2);          // 16.8 MB
  bf16_t* WguSP = (bf16_t*)alloc((size_t)GUP * DMODEL * 2);             // 4.2 MB
  bf16_t* WdSP  = (bf16_t*)alloc((size_t)DMODEL * AP * 2);              // 2.1 MB
  bf16_t* WguEP = (bf16_t*)alloc((size_t)NEXP * GUP * DMODEL * 2);      // 33.6 MB
  bf16_t* WdEP  = (bf16_t*)alloc((size_t)NEXP * DMODEL * AP * 2);       // 16.8 MB
  bf16_t* As    = (bf16_t*)alloc((size_t)TOKENS * AP * 2);              // 16.8 MB
  bf16_t* Ar    = (bf16_t*)alloc((size_t)CAP_ROWS * AP * 2);            // 35.7 MB
  bf16_t* Yr    = (bf16_t*)alloc((size_t)CAP_ROWS * DMODEL * 2);        // 35.7 MB
  int*    e01    = (int*)alloc(TOKENS * 2 * 4);
  float*  w01    = (float*)alloc(TOKENS * 2 * 4);
  int*    slotOf = (int*)alloc(TOKENS * 2 * 4);
  int*    blkCnt = (int*)alloc(PLAN_BLOCKS * NEXP * 4);
  int*    blkBas = (int*)alloc(PLAN_BLOCKS * NEXP * 4);
  int*    nTiles = (int*)alloc(64);
  int*    tileEx = (int*)alloc(MAX_TILES * 4);
  int*    rowTok = (int*)alloc(CAP_ROWS * 4);
  float*  rowW   = (float*)alloc(CAP_ROWS * 4);
  (void)ws_size; (void)in_sizes; (void)n_in; (void)out_size;

  // weight re-layout (padded)
  conv_gu_pad<<<2048, 256, 0, stream>>>((const float4*)SGU, (ushort4*)WguSP);
  conv_gu_pad<<<NEXP * 2048, 256, 0, stream>>>((const float4*)EGU, (ushort4*)WguEP);
  conv_dn_pad<<<4096, 256, 0, stream>>>(SD, WdSP);
  conv_dn_pad<<<NEXP * 4096, 256, 0, stream>>>(ED, WdEP);

  // routing
  init_kernel<<<(CAP_ROWS + 255) / 256, 256, 0, stream>>>(rowTok);
  router_kernel<<<TOKENS / 4, 256, 0, stream>>>(
      (const float4*)X, (const float4*)GW, Xb, e01, w01);
  hist_kernel<<<PLAN_BLOCKS, 256, 0, stream>>>(e01, blkCnt);
  offsets_kernel<<<1, 64, 0, stream>>>(blkCnt, blkBas, tileEx, nTiles);
  scatter_kernel<<<PLAN_BLOCKS, 256, 0, stream>>>(e01, w01, blkBas, rowTok, rowW, slotOf);

  // GEMMs: f fastest-varying for A-tile L2 locality; f=15 of gemm1 is pure pad.
  gemm1_fused<<<dim3(15, TOT_TILES), 256, 0, stream>>>(
      Xb, WguSP, WguEP, As, Ar, rowTok, tileEx, nTiles);
  gemm2_fused<<<dim3(8, TOT_TILES), 256, 0, stream>>>(
      As, Ar, WdSP, WdEP, Out, Yr, rowW, tileEx, nTiles);
  combine_kernel<<<TOKENS, 256, 0, stream>>>((float4*)Out, (const ushort4*)Yr, slotOf);
}

// Round 6
// 446.489 us; speedup vs baseline: 1.1767x; 1.0366x over previous
//
#include <hip/hip_runtime.h>
#include <hip/hip_bf16.h>
#include <stdint.h>

// MoE: B=4,S=2048,D=1024,E=8,TOPK=2,I=938. Sparse top-2 routing + bf16 MFMA GEMMs.
// R6: expert<->XCD affinity via device-built work lists (bid%8 = XCD residue):
//     routed tiles of expert e pinned to residue e (expert W hits ONE L2);
//     shared tiles residue mt%8 with f-inner order (A-tile fetched once/XCD).
//     Tiles unchanged from R5 (occupancy-proven). plan_kernel parallelizes the
//     old single-thread offsets pass.

typedef __bf16 bf16_t;
typedef __bf16 bf16x8 __attribute__((ext_vector_type(8)));
typedef float  f32x4  __attribute__((ext_vector_type(4)));

#define TOKENS    8192
#define DMODEL    1024
#define NEXP      8
#define INTER     938
#define AP        1024     // padded inter dim (A cols / gemm2 K / Wd cols)
#define KP2       960      // gemm2 effective K (A cols >=960 never written)
#define GUP       2048     // padded gate(1024)+up(1024) rows per expert
#define CAP_ROWS  17408    // 16384 + 8*128
#define MAX_TILES 136
#define SH_TILES  64       // 8192/128
#define BM        128
#define BK        64

#define G1SLOTS   3000     // 15 f-blocks x 200 mtiles
#define G1PER     375      // slots per XCD residue
#define G2SLOTS   1600     // 8 f-blocks x 200 mtiles
#define G2PER     200

#define PLAN_BLOCKS 16
#define TOK_PER_PLAN (TOKENS / PLAN_BLOCKS)

// ---- async global->LDS, 16B per lane; LDS dest = wave-uniform base + lane*16 ----
__device__ __forceinline__ void async16(const bf16_t* g, bf16_t* l) {
  __builtin_amdgcn_global_load_lds(
      (__attribute__((address_space(1))) void*)(g),
      (__attribute__((address_space(3))) void*)(l),
      16, 0, 0);
}

__device__ __forceinline__ unsigned short f2bu(float f) {
  bf16_t b = (bf16_t)f;
  unsigned short u;
  __builtin_memcpy(&u, &b, 2);
  return u;
}

// ---------------- weight re-layout converts ----------------
__global__ void conv_gu_pad(const float4* __restrict__ src, ushort4* __restrict__ dst) {
  int i = blockIdx.x * 256 + threadIdx.x;
  int e = i >> 19;            // GUP*256 = 2^19
  int rem = i & 524287;
  int r = rem >> 8;
  int c4 = rem & 255;
  const float4* s = src + (size_t)e * (1876 * 256);
  float4 v = {0.f, 0.f, 0.f, 0.f};
  if (r < INTER) v = s[r * 256 + c4];
  else if (r >= 1024 && r < 1024 + INTER) v = s[(r - 86) * 256 + c4];
  ushort4 o;
  o.x = f2bu(v.x); o.y = f2bu(v.y); o.z = f2bu(v.z); o.w = f2bu(v.w);
  dst[i] = o;
}

__global__ void conv_dn_pad(const float* __restrict__ src, bf16_t* __restrict__ dst) {
  int i = blockIdx.x * 256 + threadIdx.x;
  int e = i >> 20;
  int rem = i & 1048575;
  int n = rem >> 10;
  int c = rem & 1023;
  float v = (c < INTER) ? src[(size_t)e * (1024 * INTER) + n * INTER + c] : 0.f;
  dst[i] = (bf16_t)v;
}

// ---------------- routing ----------------
__global__ void init_kernel(int* __restrict__ row_token) {
  int i = blockIdx.x * 256 + threadIdx.x;
  if (i < CAP_ROWS) row_token[i] = -1;
}

__global__ __launch_bounds__(256) void router_kernel(
    const float4* __restrict__ X4, const float4* __restrict__ GW4,
    bf16_t* __restrict__ Xb, int* __restrict__ e01, float* __restrict__ w01) {
  int token = blockIdx.x * 4 + (threadIdx.x >> 6);
  int lane = threadIdx.x & 63;
  const float4* x4 = X4 + (size_t)token * 256;

  float4 xv[4];
#pragma unroll
  for (int j = 0; j < 4; j++) xv[j] = x4[lane + 64 * j];

  ushort4* xbrow = (ushort4*)(Xb + (size_t)token * DMODEL);
#pragma unroll
  for (int j = 0; j < 4; j++) {
    ushort4 r;
    r.x = f2bu(xv[j].x); r.y = f2bu(xv[j].y);
    r.z = f2bu(xv[j].z); r.w = f2bu(xv[j].w);
    xbrow[lane + 64 * j] = r;
  }

  float acc[NEXP];
#pragma unroll
  for (int e = 0; e < NEXP; e++) {
    float a = 0.f;
#pragma unroll
    for (int j = 0; j < 4; j++) {
      float4 g = GW4[e * 256 + lane + 64 * j];
      a += xv[j].x * g.x + xv[j].y * g.y + xv[j].z * g.z + xv[j].w * g.w;
    }
    acc[e] = a;
  }
#pragma unroll
  for (int off = 32; off > 0; off >>= 1)
#pragma unroll
    for (int e = 0; e < NEXP; e++) acc[e] += __shfl_down(acc[e], off, 64);

  if (lane == 0) {
    float mx = acc[0];
#pragma unroll
    for (int e = 1; e < NEXP; e++) mx = fmaxf(mx, acc[e]);
    float p[NEXP]; float s = 0.f;
#pragma unroll
    for (int e = 0; e < NEXP; e++) { p[e] = expf(acc[e] - mx); s += p[e]; }
    int i0 = 0;
#pragma unroll
    for (int e = 1; e < NEXP; e++) if (p[e] > p[i0]) i0 = e;
    int i1 = (i0 == 0) ? 1 : 0;
#pragma unroll
    for (int e = 0; e < NEXP; e++) if (e != i1 && e != i0 && p[e] > p[i1]) i1 = e;
    float p0 = p[i0] / s, p1 = p[i1] / s;
    float inv = 1.f / (p0 + p1 + 1e-8f);
    e01[token * 2 + 0] = i0; e01[token * 2 + 1] = i1;
    w01[token * 2 + 0] = p0 * inv; w01[token * 2 + 1] = p1 * inv;
  }
}

__global__ void hist_kernel(const int* __restrict__ e01, int* __restrict__ blockCounts) {
  __shared__ int h[NEXP];
  int t = threadIdx.x;
  if (t < NEXP) h[t] = 0;
  __syncthreads();
  int base = blockIdx.x * TOK_PER_PLAN * 2;
  for (int i = t; i < TOK_PER_PLAN * 2; i += 256) atomicAdd(&h[e01[base + i]], 1);
  __syncthreads();
  if (t < NEXP) blockCounts[blockIdx.x * NEXP + t] = h[t];
}

// ---------------- plan: blockBase, tileExpert, XCD-affine work lists ----------------
__global__ __launch_bounds__(256) void plan_kernel(
    const int* __restrict__ blockCounts, int* __restrict__ blockBase,
    int* __restrict__ tileExpert, int* __restrict__ work1, int* __restrict__ work2) {
  __shared__ int cnt[8], tc[8], tb[8], n1[8], n2[8];
  __shared__ int nT, f1n, f2n, f1c, f2c;
  __shared__ short free1[G1SLOTS];
  __shared__ short free2[G2SLOTS];
  const int t = threadIdx.x;

  if (t < 8) {
    int s = 0;
    for (int b = 0; b < PLAN_BLOCKS; b++) s += blockCounts[b * 8 + t];
    cnt[t] = s;
  }
  if (t == 0) { f1n = 0; f2n = 0; f1c = 0; f2c = 0; }
  __syncthreads();
  if (t == 0) {
    int o = 0;
    for (int e = 0; e < 8; e++) {
      tb[e] = o;
      tc[e] = (cnt[e] + BM - 1) / BM;
      o += tc[e];
    }
    nT = o;
    for (int s = 0; s < 8; s++) { n1[s] = 120 + 15 * tc[s]; n2[s] = 64 + 8 * tc[s]; }
  }
  __syncthreads();

  if (t < 8) {            // blockBase for scatter
    int run = tb[t] * BM;
    for (int b = 0; b < PLAN_BLOCKS; b++) {
      blockBase[b * 8 + t] = run;
      run += blockCounts[b * 8 + t];
    }
  }
  for (int i = t; i < MAX_TILES; i += 256) {   // tileExpert
    int e = 0;
#pragma unroll
    for (int x = 1; x < 8; x++) if (i >= tb[x]) e = x;
    tileExpert[i] = e;
  }
  for (int i = t; i < G1SLOTS; i += 256) work1[i] = -1;
  for (int i = t; i < G2SLOTS; i += 256) work2[i] = -1;
  __syncthreads();

  // own-rank fills. gemm1 shared: residue mt&7, rank (mt>>3)*15+f  (always <375)
  for (int i = t; i < 960; i += 256) {
    int mt = i / 15, f = i % 15;
    work1[(mt & 7) + 8 * ((mt >> 3) * 15 + f)] = (mt << 4) | f;
  }
  for (int i = t; i < 15 * nT; i += 256) {     // gemm1 routed: residue = expert
    int tt = i / 15, f = i % 15;
    int e = 0;
#pragma unroll
    for (int x = 1; x < 8; x++) if (tt >= tb[x]) e = x;
    int r = 120 + (tt - tb[e]) * 15 + f;
    if (r < G1PER) work1[e + 8 * r] = ((SH_TILES + tt) << 4) | f;
  }
  for (int i = t; i < 512; i += 256) {         // gemm2 shared
    int mt = i >> 3, f = i & 7;
    work2[(mt & 7) + 8 * ((mt >> 3) * 8 + f)] = (mt << 4) | f;
  }
  for (int i = t; i < 8 * nT; i += 256) {      // gemm2 routed
    int tt = i >> 3, f = i & 7;
    int e = 0;
#pragma unroll
    for (int x = 1; x < 8; x++) if (tt >= tb[x]) e = x;
    int r = 64 + (tt - tb[e]) * 8 + f;
    if (r < G2PER) work2[e + 8 * r] = ((SH_TILES + tt) << 4) | f;
  }
  __syncthreads();

  // free slots (residues whose own list is short)
  for (int i = t; i < G1SLOTS; i += 256)
    if ((i >> 3) >= n1[i & 7]) free1[atomicAdd(&f1n, 1)] = (short)i;
  for (int i = t; i < G2SLOTS; i += 256)
    if ((i >> 3) >= n2[i & 7]) free2[atomicAdd(&f2n, 1)] = (short)i;
  __syncthreads();

  // overflow items (imbalanced experts) -> spill into free slots
  for (int i = t; i < 15 * nT; i += 256) {
    int tt = i / 15, f = i % 15;
    int e = 0;
#pragma unroll
    for (int x = 1; x < 8; x++) if (tt >= tb[x]) e = x;
    int r = 120 + (tt - tb[e]) * 15 + f;
    if (r >= G1PER) work1[free1[atomicAdd(&f1c, 1)]] = ((SH_TILES + tt) << 4) | f;
  }
  for (int i = t; i < 8 * nT; i += 256) {
    int tt = i >> 3, f = i & 7;
    int e = 0;
#pragma unroll
    for (int x = 1; x < 8; x++) if (tt >= tb[x]) e = x;
    int r = 64 + (tt - tb[e]) * 8 + f;
    if (r >= G2PER) work2[free2[atomicAdd(&f2c, 1)]] = ((SH_TILES + tt) << 4) | f;
  }
}

// block-local ranks via LDS atomics; emits slotOf (token -> its 2 slot rows)
__global__ void scatter_kernel(const int* __restrict__ e01, const float* __restrict__ w01,
                               const int* __restrict__ blockBase,
                               int* __restrict__ row_token, float* __restrict__ row_weight,
                               int* __restrict__ slotOf) {
  __shared__ int cur[NEXP];
  __shared__ int base[NEXP];
  int t = threadIdx.x;
  if (t < NEXP) { cur[t] = 0; base[t] = blockBase[blockIdx.x * NEXP + t]; }
  __syncthreads();
  int tb = blockIdx.x * TOK_PER_PLAN;
  for (int i = t; i < TOK_PER_PLAN * 2; i += 256) {
    int e = e01[tb * 2 + i];
    int rank = atomicAdd(&cur[e], 1);
    int pos = base[e] + rank;
    row_token[pos] = tb + (i >> 1);
    row_weight[pos] = w01[tb * 2 + i];
    slotOf[tb * 2 + i] = pos;
  }
}

// ---------------- GEMM1 (fused shared+routed): A[M,960] = swiglu(X @ Wgu^T) ----------------
// tile 128 x (64 gate + 64 up), BK=64; 4 waves 2x2; XOR-swizzled LDS; work-list driven.
__global__ __launch_bounds__(256) void gemm1_fused(
    const bf16_t* __restrict__ Xb, const bf16_t* __restrict__ WS,
    const bf16_t* __restrict__ WE, bf16_t* __restrict__ As, bf16_t* __restrict__ Ar,
    const int* __restrict__ row_token, const int* __restrict__ tileExpert,
    const int* __restrict__ work1) {
  const int item = work1[blockIdx.x];
  if (item < 0) return;
  const int mt = item >> 4;
  const int f0 = (item & 15) * 64;

  const bf16_t* W; bf16_t* Aout; int m0; const int* rtok = nullptr;
  if (mt < SH_TILES) {
    m0 = mt * BM; W = WS; Aout = As;
  } else {
    int rt = mt - SH_TILES;
    m0 = rt * BM; W = WE + (size_t)tileExpert[rt] * (GUP * DMODEL);
    Aout = Ar; rtok = row_token;
  }

  __shared__ bf16_t sA[BM * BK];    // 16KB
  __shared__ bf16_t sBg[64 * BK];   // 8KB
  __shared__ bf16_t sBu[64 * BK];   // 8KB

  const int tid = threadIdx.x;
  const int w = tid >> 6, lane = tid & 63;

  const bf16_t* aptr[4];
#pragma unroll
  for (int i = 0; i < 4; i++) {
    int q = (i * 4 + w) * 64 + lane;
    int row = q >> 3, cc = ((q & 7) ^ (row & 7)) * 8;   // XOR swizzle
    int tok = m0 + row;
    if (rtok) { int t = rtok[tok]; tok = (t < 0) ? 0 : t; }
    aptr[i] = Xb + (size_t)tok * DMODEL + cc;
  }
  const bf16_t* bgp[2]; const bf16_t* bup[2];
#pragma unroll
  for (int i = 0; i < 2; i++) {
    int q = (i * 4 + w) * 64 + lane;
    int r = q >> 3, cc = ((q & 7) ^ (r & 7)) * 8;
    bgp[i] = W + (size_t)(f0 + r) * DMODEL + cc;
    bup[i] = W + (size_t)(1024 + f0 + r) * DMODEL + cc;
  }

  f32x4 accG[4][2], accU[4][2];
#pragma unroll
  for (int mi = 0; mi < 4; mi++)
#pragma unroll
    for (int ni = 0; ni < 2; ni++) {
      accG[mi][ni] = (f32x4){0.f, 0.f, 0.f, 0.f};
      accU[mi][ni] = (f32x4){0.f, 0.f, 0.f, 0.f};
    }

  const int wm = w >> 1, wn = w & 1;
  const int lr = lane & 15, quad = lane >> 4;

  for (int k0 = 0; k0 < DMODEL; k0 += BK) {
#pragma unroll
    for (int i = 0; i < 4; i++) async16(aptr[i] + k0, &sA[(i * 4 + w) * 512]);
#pragma unroll
    for (int i = 0; i < 2; i++) {
      async16(bgp[i] + k0, &sBg[(i * 4 + w) * 512]);
      async16(bup[i] + k0, &sBu[(i * 4 + w) * 512]);
    }
    __syncthreads();
#pragma unroll
    for (int kk = 0; kk < BK; kk += 32) {
      const int colsw = (((kk >> 3) + quad) ^ (lr & 7)) * 8;
      bf16x8 av[4], bg[2], bu[2];
#pragma unroll
      for (int mi = 0; mi < 4; mi++)
        av[mi] = *(const bf16x8*)&sA[(wm * 64 + mi * 16 + lr) * BK + colsw];
#pragma unroll
      for (int ni = 0; ni < 2; ni++) {
        bg[ni] = *(const bf16x8*)&sBg[(wn * 32 + ni * 16 + lr) * BK + colsw];
        bu[ni] = *(const bf16x8*)&sBu[(wn * 32 + ni * 16 + lr) * BK + colsw];
      }
#pragma unroll
      for (int mi = 0; mi < 4; mi++)
#pragma unroll
        for (int ni = 0; ni < 2; ni++) {
          accG[mi][ni] = __builtin_amdgcn_mfma_f32_16x16x32_bf16(av[mi], bg[ni], accG[mi][ni], 0, 0, 0);
          accU[mi][ni] = __builtin_amdgcn_mfma_f32_16x16x32_bf16(av[mi], bu[ni], accU[mi][ni], 0, 0, 0);
        }
    }
    __syncthreads();
  }

  // C/D layout: col=lane&15, row=quad*4+reg
#pragma unroll
  for (int mi = 0; mi < 4; mi++)
#pragma unroll
    for (int ni = 0; ni < 2; ni++)
#pragma unroll
      for (int r = 0; r < 4; r++) {
        int row = m0 + wm * 64 + mi * 16 + quad * 4 + r;
        int col = f0 + wn * 32 + ni * 16 + lr;
        float g = accG[mi][ni][r], u = accU[mi][ni][r];
        float v = (col < INTER) ? (g / (1.f + __expf(-g))) * u : 0.f;
        Aout[(size_t)row * AP + col] = (bf16_t)v;
      }
}

// ---------------- GEMM2 (fused shared+routed): 128x128 tile, K=960 ----------------
__global__ __launch_bounds__(256) void gemm2_fused(
    const bf16_t* __restrict__ As, const bf16_t* __restrict__ Ar,
    const bf16_t* __restrict__ WS, const bf16_t* __restrict__ WE,
    float* __restrict__ Out, bf16_t* __restrict__ Yr,
    const float* __restrict__ row_weight, const int* __restrict__ tileExpert,
    const int* __restrict__ work2) {
  const int item = work2[blockIdx.x];
  if (item < 0) return;
  const int mt = item >> 4;
  const int n0 = (item & 15) * 128;

  const bf16_t* A; const bf16_t* W; int m0; bool routed;
  if (mt < SH_TILES) {
    routed = false; m0 = mt * BM; A = As; W = WS;
  } else {
    int rt = mt - SH_TILES;
    routed = true; m0 = rt * BM; A = Ar;
    W = WE + (size_t)tileExpert[rt] * (DMODEL * AP);
  }

  __shared__ bf16_t sA[128 * BK];   // 16KB
  __shared__ bf16_t sB[128 * BK];   // 16KB

  const int tid = threadIdx.x;
  const int w = tid >> 6, lane = tid & 63;

  const bf16_t* aptr[4];
#pragma unroll
  for (int i = 0; i < 4; i++) {
    int q = (i * 4 + w) * 64 + lane;
    int row = q >> 3, cc = ((q & 7) ^ (row & 7)) * 8;
    aptr[i] = A + (size_t)(m0 + row) * AP + cc;
  }
  const bf16_t* bp[4];
#pragma unroll
  for (int i = 0; i < 4; i++) {
    int q = (i * 4 + w) * 64 + lane;
    int r = q >> 3, cc = ((q & 7) ^ (r & 7)) * 8;
    bp[i] = W + (size_t)(n0 + r) * AP + cc;
  }

  f32x4 acc[4][4];
#pragma unroll
  for (int mi = 0; mi < 4; mi++)
#pragma unroll
    for (int ni = 0; ni < 4; ni++) acc[mi][ni] = (f32x4){0.f, 0.f, 0.f, 0.f};

  const int wm = w >> 1, wn = w & 1;
  const int lr = lane & 15, quad = lane >> 4;

  for (int k0 = 0; k0 < KP2; k0 += BK) {
#pragma unroll
    for (int i = 0; i < 4; i++) async16(aptr[i] + k0, &sA[(i * 4 + w) * 512]);
#pragma unroll
    for (int i = 0; i < 4; i++) async16(bp[i] + k0, &sB[(i * 4 + w) * 512]);
    __syncthreads();
#pragma unroll
    for (int kk = 0; kk < BK; kk += 32) {
      const int colsw = (((kk >> 3) + quad) ^ (lr & 7)) * 8;
      bf16x8 av[4], bv[4];
#pragma unroll
      for (int mi = 0; mi < 4; mi++)
        av[mi] = *(const bf16x8*)&sA[(wm * 64 + mi * 16 + lr) * BK + colsw];
#pragma unroll
      for (int ni = 0; ni < 4; ni++)
        bv[ni] = *(const bf16x8*)&sB[(wn * 64 + ni * 16 + lr) * BK + colsw];
#pragma unroll
      for (int mi = 0; mi < 4; mi++)
#pragma unroll
        for (int ni = 0; ni < 4; ni++)
          acc[mi][ni] = __builtin_amdgcn_mfma_f32_16x16x32_bf16(av[mi], bv[ni], acc[mi][ni], 0, 0, 0);
    }
    __syncthreads();
  }

#pragma unroll
  for (int mi = 0; mi < 4; mi++) {
#pragma unroll
    for (int r = 0; r < 4; r++) {
      int row = m0 + wm * 64 + mi * 16 + quad * 4 + r;
      float rw = routed ? row_weight[row] : 0.f;
#pragma unroll
      for (int ni = 0; ni < 4; ni++) {
        int col = n0 + wn * 64 + ni * 16 + lr;
        float v = acc[mi][ni][r];
        if (!routed) Out[(size_t)row * DMODEL + col] = v;
        else         Yr[(size_t)row * DMODEL + col] = (bf16_t)(rw * v);
      }
    }
  }
}

// ---------------- combine: Out[t] += Yr[slot0(t)] + Yr[slot1(t)] ----------------
__global__ __launch_bounds__(256) void combine_kernel(
    float4* __restrict__ Out4, const ushort4* __restrict__ Yr4,
    const int* __restrict__ slotOf) {
  int t = blockIdx.x;
  int c = threadIdx.x;
  int s0 = slotOf[t * 2 + 0];
  int s1 = slotOf[t * 2 + 1];
  float4 o = Out4[t * 256 + c];
  ushort4 a = Yr4[(size_t)s0 * 256 + c];
  ushort4 b = Yr4[(size_t)s1 * 256 + c];
  union { unsigned int u; float f; } cv;
  auto b2f = [&](unsigned short x) { cv.u = ((unsigned int)x) << 16; return cv.f; };
  o.x += b2f(a.x) + b2f(b.x);
  o.y += b2f(a.y) + b2f(b.y);
  o.z += b2f(a.z) + b2f(b.z);
  o.w += b2f(a.w) + b2f(b.w);
  Out4[t * 256 + c] = o;
}

// ---------------- launch ----------------
extern "C" void kernel_launch(void* const* d_in, const int* in_sizes, int n_in,
                              void* d_out, int out_size, void* d_ws, size_t ws_size,
                              hipStream_t stream) {
  const float* X   = (const float*)d_in[0];
  const float* GW  = (const float*)d_in[1];
  const float* SGU = (const float*)d_in[2];
  const float* SD  = (const float*)d_in[3];
  const float* EGU = (const float*)d_in[4];
  const float* ED  = (const float*)d_in[5];
  float* Out = (float*)d_out;

  char* ws = (char*)d_ws;
  size_t o = 0;
  auto alloc = [&](size_t b) -> char* {
    char* p = ws + o;
    o = (o + b + 255) & ~(size_t)255;
    return p;
  };
  bf16_t* Xb    = (bf16_t*)alloc((size_t)TOKENS * DMODEL * 2);          // 16.8 MB
  bf16_t* WguSP = (bf16_t*)alloc((size_t)GUP * DMODEL * 2);             // 4.2 MB
  bf16_t* WdSP  = (bf16_t*)alloc((size_t)DMODEL * AP * 2);              // 2.1 MB
  bf16_t* WguEP = (bf16_t*)alloc((size_t)NEXP * GUP * DMODEL * 2);      // 33.6 MB
  bf16_t* WdEP  = (bf16_t*)alloc((size_t)NEXP * DMODEL * AP * 2);       // 16.8 MB
  bf16_t* As    = (bf16_t*)alloc((size_t)TOKENS * AP * 2);              // 16.8 MB
  bf16_t* Ar    = (bf16_t*)alloc((size_t)CAP_ROWS * AP * 2);            // 35.7 MB
  bf16_t* Yr    = (bf16_t*)alloc((size_t)CAP_ROWS * DMODEL * 2);        // 35.7 MB
  int*    e01    = (int*)alloc(TOKENS * 2 * 4);
  float*  w01    = (float*)alloc(TOKENS * 2 * 4);
  int*    slotOf = (int*)alloc(TOKENS * 2 * 4);
  int*    blkCnt = (int*)alloc(PLAN_BLOCKS * NEXP * 4);
  int*    blkBas = (int*)alloc(PLAN_BLOCKS * NEXP * 4);
  int*    tileEx = (int*)alloc(MAX_TILES * 4);
  int*    work1  = (int*)alloc(G1SLOTS * 4);
  int*    work2  = (int*)alloc(G2SLOTS * 4);
  int*    rowTok = (int*)alloc(CAP_ROWS * 4);
  float*  rowW   = (float*)alloc(CAP_ROWS * 4);
  (void)ws_size; (void)in_sizes; (void)n_in; (void)out_size;

  // weight re-layout (padded)
  conv_gu_pad<<<2048, 256, 0, stream>>>((const float4*)SGU, (ushort4*)WguSP);
  conv_gu_pad<<<NEXP * 2048, 256, 0, stream>>>((const float4*)EGU, (ushort4*)WguEP);
  conv_dn_pad<<<4096, 256, 0, stream>>>(SD, WdSP);
  conv_dn_pad<<<NEXP * 4096, 256, 0, stream>>>(ED, WdEP);

  // routing
  init_kernel<<<(CAP_ROWS + 255) / 256, 256, 0, stream>>>(rowTok);
  router_kernel<<<TOKENS / 4, 256, 0, stream>>>(
      (const float4*)X, (const float4*)GW, Xb, e01, w01);
  hist_kernel<<<PLAN_BLOCKS, 256, 0, stream>>>(e01, blkCnt);
  plan_kernel<<<1, 256, 0, stream>>>(blkCnt, blkBas, tileEx, work1, work2);
  scatter_kernel<<<PLAN_BLOCKS, 256, 0, stream>>>(e01, w01, blkBas, rowTok, rowW, slotOf);

  // GEMMs: 1D grids, work-list driven with expert<->XCD affinity
  gemm1_fused<<<G1SLOTS, 256, 0, stream>>>(
      Xb, WguSP, WguEP, As, Ar, rowTok, tileEx, work1);
  gemm2_fused<<<G2SLOTS, 256, 0, stream>>>(
      As, Ar, WdSP, WdEP, Out, Yr, rowW, tileEx, work2);
  combine_kernel<<<TOKENS, 256, 0, stream>>>((float4*)Out, (const ushort4*)Yr, slotOf);
}